// Round 1
// baseline (436.127 us; speedup 1.0000x reference)
//
#include <hip/hip_runtime.h>
#include <cstdint>

#define B_DIM 16
#define C_DIM 512
#define N_DIM 4096

typedef __bf16 bf16x8 __attribute__((ext_vector_type(8)));
typedef unsigned short u16x8 __attribute__((ext_vector_type(8)));
typedef unsigned short u16x4 __attribute__((ext_vector_type(4)));
typedef float f32x4 __attribute__((ext_vector_type(4)));

__device__ __forceinline__ unsigned short f2bf_rne(float f) {
    unsigned int u = __float_as_uint(f);
    u += 0x7fffu + ((u >> 16) & 1u);
    return (unsigned short)(u >> 16);
}
__device__ __forceinline__ float bf2f(unsigned short h) {
    return __uint_as_float(((unsigned int)h) << 16);
}
__device__ __forceinline__ bf16x8 as_bf(u16x8 v) {
    return __builtin_bit_cast(bf16x8, v);
}

#define BT 128
#define BK 32
#define BKP 40  // padded LDS row (ushorts): 80B rows -> 16B aligned, 20-bank rotation

// ---------------------------------------------------------------------------
// Kernel 1: energy[b] = Q^T Q  (split bf16: hi*hi + hi*lo + lo*hi)
// Q = x[b] viewed as (N_DIM x C_DIM) row-major.
// Block computes a 128x128 tile of the (512x512) Gram matrix.
// ---------------------------------------------------------------------------
__global__ __launch_bounds__(256) void gram_kernel(const float* __restrict__ x,
                                                   float* __restrict__ energy) {
    const int b = blockIdx.z;
    const int c0 = blockIdx.x * BT;
    const int d0 = blockIdx.y * BT;
    const float* __restrict__ Q = x + (size_t)b * (N_DIM * C_DIM);
    float* __restrict__ E = energy + (size_t)b * (C_DIM * C_DIM);

    __shared__ unsigned short lAh[BT][BKP];
    __shared__ unsigned short lAl[BT][BKP];
    __shared__ unsigned short lBh[BT][BKP];
    __shared__ unsigned short lBl[BT][BKP];

    const int tid = threadIdx.x;
    const int lane = tid & 63;
    const int w = tid >> 6;
    const int moff = (w & 1) * 64;
    const int noff = (w >> 1) * 64;
    const int frow = lane & 15;
    const int fk = (lane >> 4) * 8;

    f32x4 acc[4][4];
#pragma unroll
    for (int m = 0; m < 4; ++m)
#pragma unroll
        for (int n = 0; n < 4; ++n) acc[m][n] = (f32x4){0.f, 0.f, 0.f, 0.f};

    // staging: thread owns column cc of the tile, 16 consecutive k rows
    const int cc = tid & 127;
    const int kh = tid >> 7;  // 0 or 1

    const float* gA = Q + (size_t)(kh * 16) * C_DIM + (c0 + cc);
    const float* gB = Q + (size_t)(kh * 16) * C_DIM + (d0 + cc);

    for (int k0 = 0; k0 < N_DIM; k0 += BK) {
        u16x8 vah[2], val[2], vbh[2], vbl[2];
#pragma unroll
        for (int i = 0; i < 16; ++i) {
            float fa = gA[(size_t)i * C_DIM];
            float fb = gB[(size_t)i * C_DIM];
            unsigned short ah = f2bf_rne(fa);
            unsigned short al = f2bf_rne(fa - bf2f(ah));
            unsigned short bh = f2bf_rne(fb);
            unsigned short bl = f2bf_rne(fb - bf2f(bh));
            vah[i >> 3][i & 7] = ah;
            val[i >> 3][i & 7] = al;
            vbh[i >> 3][i & 7] = bh;
            vbl[i >> 3][i & 7] = bl;
        }
        gA += (size_t)BK * C_DIM;
        gB += (size_t)BK * C_DIM;

        __syncthreads();  // previous iteration's LDS reads done
        *(u16x8*)&lAh[cc][kh * 16]     = vah[0];
        *(u16x8*)&lAh[cc][kh * 16 + 8] = vah[1];
        *(u16x8*)&lAl[cc][kh * 16]     = val[0];
        *(u16x8*)&lAl[cc][kh * 16 + 8] = val[1];
        *(u16x8*)&lBh[cc][kh * 16]     = vbh[0];
        *(u16x8*)&lBh[cc][kh * 16 + 8] = vbh[1];
        *(u16x8*)&lBl[cc][kh * 16]     = vbl[0];
        *(u16x8*)&lBl[cc][kh * 16 + 8] = vbl[1];
        __syncthreads();

        bf16x8 fa_h[4], fa_l[4], fb_h[4], fb_l[4];
#pragma unroll
        for (int m = 0; m < 4; ++m) {
            fa_h[m] = as_bf(*(const u16x8*)&lAh[moff + m * 16 + frow][fk]);
            fa_l[m] = as_bf(*(const u16x8*)&lAl[moff + m * 16 + frow][fk]);
        }
#pragma unroll
        for (int n = 0; n < 4; ++n) {
            fb_h[n] = as_bf(*(const u16x8*)&lBh[noff + n * 16 + frow][fk]);
            fb_l[n] = as_bf(*(const u16x8*)&lBl[noff + n * 16 + frow][fk]);
        }
#pragma unroll
        for (int m = 0; m < 4; ++m)
#pragma unroll
            for (int n = 0; n < 4; ++n) {
                acc[m][n] = __builtin_amdgcn_mfma_f32_16x16x32_bf16(fa_h[m], fb_h[n], acc[m][n], 0, 0, 0);
                acc[m][n] = __builtin_amdgcn_mfma_f32_16x16x32_bf16(fa_h[m], fb_l[n], acc[m][n], 0, 0, 0);
                acc[m][n] = __builtin_amdgcn_mfma_f32_16x16x32_bf16(fa_l[m], fb_h[n], acc[m][n], 0, 0, 0);
            }
    }

#pragma unroll
    for (int m = 0; m < 4; ++m)
#pragma unroll
        for (int n = 0; n < 4; ++n) {
            const int r = c0 + moff + m * 16 + (lane >> 4) * 4;
            const int col = d0 + noff + n * 16 + frow;
#pragma unroll
            for (int i = 0; i < 4; ++i)
                E[(size_t)(r + i) * C_DIM + col] = acc[m][n][i];
        }
}

// ---------------------------------------------------------------------------
// Kernel 2: mx[d] = max_c energy[0, c, d]   (batch 0 only!)
// ---------------------------------------------------------------------------
__global__ void colmax_kernel(const float* __restrict__ energy, float* __restrict__ mx) {
    const int d = blockIdx.x * 256 + threadIdx.x;
    float m = -3.4e38f;
    for (int c = 0; c < C_DIM; ++c) m = fmaxf(m, energy[(size_t)c * C_DIM + d]);
    mx[d] = m;
}

// ---------------------------------------------------------------------------
// Kernel 3: in-place row softmax of (mx[d] - energy[b,c,d]) over d.
// One wave per row; 8 elements per lane.
// ---------------------------------------------------------------------------
__global__ __launch_bounds__(256) void softmax_kernel(float* __restrict__ energy,
                                                      const float* __restrict__ mx) {
    const int wid = blockIdx.x * 4 + (threadIdx.x >> 6);  // row index in [0, B*C)
    const int lane = threadIdx.x & 63;
    float* __restrict__ row = energy + (size_t)wid * C_DIM;

    float4 a = *(const float4*)&row[lane * 8];
    float4 b = *(const float4*)&row[lane * 8 + 4];
    float4 ma = *(const float4*)&mx[lane * 8];
    float4 mb = *(const float4*)&mx[lane * 8 + 4];

    float v[8];
    v[0] = ma.x - a.x; v[1] = ma.y - a.y; v[2] = ma.z - a.z; v[3] = ma.w - a.w;
    v[4] = mb.x - b.x; v[5] = mb.y - b.y; v[6] = mb.z - b.z; v[7] = mb.w - b.w;

    float rm = v[0];
#pragma unroll
    for (int j = 1; j < 8; ++j) rm = fmaxf(rm, v[j]);
#pragma unroll
    for (int s = 1; s < 64; s <<= 1) rm = fmaxf(rm, __shfl_xor(rm, s));

    float p[8];
    float sum = 0.f;
#pragma unroll
    for (int j = 0; j < 8; ++j) {
        p[j] = expf(v[j] - rm);
        sum += p[j];
    }
#pragma unroll
    for (int s = 1; s < 64; s <<= 1) sum += __shfl_xor(sum, s);

    const float inv = 1.f / sum;
    float4 o0 = {p[0] * inv, p[1] * inv, p[2] * inv, p[3] * inv};
    float4 o1 = {p[4] * inv, p[5] * inv, p[6] * inv, p[7] * inv};
    *(float4*)&row[lane * 8] = o0;
    *(float4*)&row[lane * 8 + 4] = o1;
}

// ---------------------------------------------------------------------------
// Kernel 4: out[b,c,n] = gamma * sum_d att[b,c,d] * Q[n,d] + x[b,c,n]
// M=C_DIM (c), N=N_DIM (n), K=C_DIM (d). Plain bf16 MFMA.
// ---------------------------------------------------------------------------
__global__ __launch_bounds__(256) void gemm2_kernel(const float* __restrict__ att,
                                                    const float* __restrict__ x,
                                                    const float* __restrict__ gamma,
                                                    float* __restrict__ out) {
    const int b = blockIdx.z;
    const int c0 = blockIdx.x * BT;  // M tile
    const int n0 = blockIdx.y * BT;  // N tile
    const float* __restrict__ A = att + (size_t)b * (C_DIM * C_DIM);
    const float* __restrict__ Q = x + (size_t)b * (N_DIM * C_DIM);
    const float* __restrict__ Xb = Q;  // same layout: b*C*N flat
    float* __restrict__ Ob = out + (size_t)b * (C_DIM * N_DIM);

    __shared__ unsigned short lA[BT][BKP];
    __shared__ unsigned short lB[BT][BKP];

    const int tid = threadIdx.x;
    const int lane = tid & 63;
    const int w = tid >> 6;
    const int moff = (w & 1) * 64;
    const int noff = (w >> 1) * 64;
    const int frow = lane & 15;
    const int fk = (lane >> 4) * 8;

    f32x4 acc[4][4];
#pragma unroll
    for (int m = 0; m < 4; ++m)
#pragma unroll
        for (int n = 0; n < 4; ++n) acc[m][n] = (f32x4){0.f, 0.f, 0.f, 0.f};

    for (int k0 = 0; k0 < C_DIM; k0 += BK) {
        float4 ra[4], rb[4];
#pragma unroll
        for (int i = 0; i < 4; ++i) {
            const int f = tid + 256 * i;   // flat float4 index, 1024 per tile
            const int rr = f >> 3;         // tile row 0..127
            const int k4 = (f & 7) * 4;    // k offset 0..28
            ra[i] = *(const float4*)&A[(size_t)(c0 + rr) * C_DIM + k0 + k4];
            rb[i] = *(const float4*)&Q[(size_t)(n0 + rr) * C_DIM + k0 + k4];
        }
        __syncthreads();
#pragma unroll
        for (int i = 0; i < 4; ++i) {
            const int f = tid + 256 * i;
            const int rr = f >> 3;
            const int k4 = (f & 7) * 4;
            u16x4 pa = {f2bf_rne(ra[i].x), f2bf_rne(ra[i].y), f2bf_rne(ra[i].z), f2bf_rne(ra[i].w)};
            u16x4 pb = {f2bf_rne(rb[i].x), f2bf_rne(rb[i].y), f2bf_rne(rb[i].z), f2bf_rne(rb[i].w)};
            *(u16x4*)&lA[rr][k4] = pa;
            *(u16x4*)&lB[rr][k4] = pb;
        }
        __syncthreads();

        bf16x8 fa[4], fb[4];
#pragma unroll
        for (int m = 0; m < 4; ++m)
            fa[m] = as_bf(*(const u16x8*)&lA[moff + m * 16 + frow][fk]);
#pragma unroll
        for (int n = 0; n < 4; ++n)
            fb[n] = as_bf(*(const u16x8*)&lB[noff + n * 16 + frow][fk]);
#pragma unroll
        for (int m = 0; m < 4; ++m)
#pragma unroll
            for (int n = 0; n < 4; ++n)
                acc[m][n] = __builtin_amdgcn_mfma_f32_16x16x32_bf16(fa[m], fb[n], acc[m][n], 0, 0, 0);
    }

    const float g = gamma[0];
#pragma unroll
    for (int m = 0; m < 4; ++m)
#pragma unroll
        for (int n = 0; n < 4; ++n) {
            const int r = c0 + moff + m * 16 + (lane >> 4) * 4;
            const int col = n0 + noff + n * 16 + frow;
#pragma unroll
            for (int i = 0; i < 4; ++i) {
                const size_t idx = (size_t)(r + i) * N_DIM + col;
                Ob[idx] = g * acc[m][n][i] + Xb[idx];
            }
        }
}

// ---------------------------------------------------------------------------
extern "C" void kernel_launch(void* const* d_in, const int* in_sizes, int n_in,
                              void* d_out, int out_size, void* d_ws, size_t ws_size,
                              hipStream_t stream) {
    const float* x = (const float*)d_in[0];
    const float* gamma = (const float*)d_in[1];
    float* out = (float*)d_out;

    float* energy = (float*)d_ws;                                  // 16*512*512 f32 = 16.78 MB
    float* mx = energy + (size_t)B_DIM * C_DIM * C_DIM;            // 512 f32

    dim3 g1(C_DIM / BT, C_DIM / BT, B_DIM);  // (4,4,16)
    gram_kernel<<<g1, 256, 0, stream>>>(x, energy);

    colmax_kernel<<<C_DIM / 256, 256, 0, stream>>>(energy, mx);

    softmax_kernel<<<(B_DIM * C_DIM) / 4, 256, 0, stream>>>(energy, mx);

    dim3 g2(C_DIM / BT, N_DIM / BT, B_DIM);  // (4,32,16)
    gemm2_kernel<<<g2, 256, 0, stream>>>(energy, x, gamma, out);
}

// Round 2
// 291.048 us; speedup vs baseline: 1.4985x; 1.4985x over previous
//
#include <hip/hip_runtime.h>
#include <cstdint>

#define B_DIM 16
#define C_DIM 512
#define N_DIM 4096

typedef __bf16 bf16x8 __attribute__((ext_vector_type(8)));
typedef unsigned short u16x8 __attribute__((ext_vector_type(8)));
typedef unsigned short u16x4 __attribute__((ext_vector_type(4)));
typedef float f32x4 __attribute__((ext_vector_type(4)));

__device__ __forceinline__ unsigned short f2bf_tr(float f) {
    return (unsigned short)(__float_as_uint(f) >> 16);
}
__device__ __forceinline__ bf16x8 as_bf(u16x8 v) {
    return __builtin_bit_cast(bf16x8, v);
}

#define BT 128
#define BK 32
#define BKP 40  // padded LDS row (ushorts): 80B rows, 16B-aligned

// ---------------------------------------------------------------------------
// Kernel 1: partial Gram  E_s[c,d] = sum_{n in slice s} Q[n,c] Q[n,d]
// Split bf16 (truncating): E ~ hi*hi + hi*lo + lo*hi.
// Symmetry: only upper-triangle tiles computed; off-diag mirrored on store.
// grid = (10, 1, B*SK)
// ---------------------------------------------------------------------------
__global__ __launch_bounds__(256) void gram_kernel(const float* __restrict__ x,
                                                   float* __restrict__ part, int kshift) {
    const int sk = 1 << kshift;
    const int s = blockIdx.z & (sk - 1);
    const int b = blockIdx.z >> kshift;
    static const int TI[10] = {0, 0, 0, 0, 1, 1, 1, 2, 2, 3};
    static const int TJ[10] = {0, 1, 2, 3, 1, 2, 3, 2, 3, 3};
    const int c0 = TI[blockIdx.x] * BT;
    const int d0 = TJ[blockIdx.x] * BT;
    const bool diag = (c0 == d0);

    const float* __restrict__ Q = x + (size_t)b * (N_DIM * C_DIM);
    float* __restrict__ E = part + ((size_t)s * B_DIM + b) * (C_DIM * C_DIM);

    __shared__ unsigned short lAh[BT][BKP];
    __shared__ unsigned short lAl[BT][BKP];
    __shared__ unsigned short lBh[BT][BKP];
    __shared__ unsigned short lBl[BT][BKP];

    const int tid = threadIdx.x;
    const int lane = tid & 63;
    const int w = tid >> 6;
    const int moff = (w & 1) * 64;
    const int noff = (w >> 1) * 64;
    const int frow = lane & 15;
    const int fk = (lane >> 4) * 8;

    f32x4 acc[4][4];
#pragma unroll
    for (int m = 0; m < 4; ++m)
#pragma unroll
        for (int n = 0; n < 4; ++n) acc[m][n] = (f32x4){0.f, 0.f, 0.f, 0.f};

    const int cc = tid & 127;  // tile column owned by this thread
    const int kh = tid >> 7;   // 0/1: which 16-row half of the K-step

    const int klen = N_DIM >> kshift;
    const int kbeg = s * klen;
    const float* gA = Q + (size_t)(kbeg + kh * 16) * C_DIM + (c0 + cc);
    const float* gB = Q + (size_t)(kbeg + kh * 16) * C_DIM + (d0 + cc);

    const unsigned short(*pBh)[BKP] = diag ? lAh : lBh;
    const unsigned short(*pBl)[BKP] = diag ? lAl : lBl;

    for (int k0 = 0; k0 < klen; k0 += BK) {
        u16x8 vah[2], val[2], vbh[2], vbl[2];
#pragma unroll
        for (int i = 0; i < 16; ++i) {
            float fa = gA[(size_t)i * C_DIM];
            unsigned int ua = __float_as_uint(fa);
            unsigned short ah = (unsigned short)(ua >> 16);
            float rsa = fa - __uint_as_float(ua & 0xffff0000u);
            unsigned short al = (unsigned short)(__float_as_uint(rsa) >> 16);
            vah[i >> 3][i & 7] = ah;
            val[i >> 3][i & 7] = al;
        }
        if (!diag) {
#pragma unroll
            for (int i = 0; i < 16; ++i) {
                float fb = gB[(size_t)i * C_DIM];
                unsigned int ub = __float_as_uint(fb);
                unsigned short bh = (unsigned short)(ub >> 16);
                float rsb = fb - __uint_as_float(ub & 0xffff0000u);
                unsigned short bl = (unsigned short)(__float_as_uint(rsb) >> 16);
                vbh[i >> 3][i & 7] = bh;
                vbl[i >> 3][i & 7] = bl;
            }
        }
        gA += (size_t)BK * C_DIM;
        gB += (size_t)BK * C_DIM;

        __syncthreads();  // previous iteration's LDS reads done
        *(u16x8*)&lAh[cc][kh * 16]     = vah[0];
        *(u16x8*)&lAh[cc][kh * 16 + 8] = vah[1];
        *(u16x8*)&lAl[cc][kh * 16]     = val[0];
        *(u16x8*)&lAl[cc][kh * 16 + 8] = val[1];
        if (!diag) {
            *(u16x8*)&lBh[cc][kh * 16]     = vbh[0];
            *(u16x8*)&lBh[cc][kh * 16 + 8] = vbh[1];
            *(u16x8*)&lBl[cc][kh * 16]     = vbl[0];
            *(u16x8*)&lBl[cc][kh * 16 + 8] = vbl[1];
        }
        __syncthreads();

        bf16x8 fa_h[4], fa_l[4], fb_h[4], fb_l[4];
#pragma unroll
        for (int m = 0; m < 4; ++m) {
            fa_h[m] = as_bf(*(const u16x8*)&lAh[moff + m * 16 + frow][fk]);
            fa_l[m] = as_bf(*(const u16x8*)&lAl[moff + m * 16 + frow][fk]);
        }
#pragma unroll
        for (int n = 0; n < 4; ++n) {
            fb_h[n] = as_bf(*(const u16x8*)&pBh[noff + n * 16 + frow][fk]);
            fb_l[n] = as_bf(*(const u16x8*)&pBl[noff + n * 16 + frow][fk]);
        }
#pragma unroll
        for (int m = 0; m < 4; ++m)
#pragma unroll
            for (int n = 0; n < 4; ++n) {
                acc[m][n] = __builtin_amdgcn_mfma_f32_16x16x32_bf16(fa_h[m], fb_h[n], acc[m][n], 0, 0, 0);
                acc[m][n] = __builtin_amdgcn_mfma_f32_16x16x32_bf16(fa_h[m], fb_l[n], acc[m][n], 0, 0, 0);
                acc[m][n] = __builtin_amdgcn_mfma_f32_16x16x32_bf16(fa_l[m], fb_h[n], acc[m][n], 0, 0, 0);
            }
    }

#pragma unroll
    for (int m = 0; m < 4; ++m)
#pragma unroll
        for (int n = 0; n < 4; ++n) {
            const int r = c0 + moff + m * 16 + (lane >> 4) * 4;
            const int col = d0 + noff + n * 16 + frow;
#pragma unroll
            for (int i = 0; i < 4; ++i)
                E[(size_t)(r + i) * C_DIM + col] = acc[m][n][i];
        }
    if (!diag) {
        // mirror: E[d,c] = E[c,d]
#pragma unroll
        for (int m = 0; m < 4; ++m)
#pragma unroll
            for (int n = 0; n < 4; ++n) {
                const int r = c0 + moff + m * 16 + (lane >> 4) * 4;
                const int col = d0 + noff + n * 16 + frow;
#pragma unroll
                for (int i = 0; i < 4; ++i)
                    E[(size_t)col * C_DIM + (r + i)] = acc[m][n][i];
            }
    }
}

// ---------------------------------------------------------------------------
// Kernel 2a: partial colmax over 64-row chunks of batch-0 energy.
// grid = (2, 8): d = bx*256+tx, rows [by*64, by*64+64)
// ---------------------------------------------------------------------------
__global__ __launch_bounds__(256) void colmax1(const float* __restrict__ part,
                                               float* __restrict__ pmax, int sk) {
    const int d = blockIdx.x * 256 + threadIdx.x;
    const int cg = blockIdx.y;
    const size_t PS = (size_t)B_DIM * C_DIM * C_DIM;
    float m = -3.4e38f;
    for (int c = cg * 64; c < cg * 64 + 64; ++c) {
        float e = 0.f;
        for (int s = 0; s < sk; ++s) e += part[(size_t)s * PS + (size_t)c * C_DIM + d];
        m = fmaxf(m, e);
    }
    pmax[cg * C_DIM + d] = m;
}

// Kernel 2b: reduce the 8 partial maxima. grid = 2 blocks.
__global__ __launch_bounds__(256) void colmax2(const float* __restrict__ pmax,
                                               float* __restrict__ mx) {
    const int d = blockIdx.x * 256 + threadIdx.x;
    float m = pmax[d];
#pragma unroll
    for (int g = 1; g < 8; ++g) m = fmaxf(m, pmax[g * C_DIM + d]);
    mx[d] = m;
}

// ---------------------------------------------------------------------------
// Kernel 3: row softmax of (mx[d] - sum_s E_s[b,c,d]); result into partial 0.
// One wave per row; 8 elements per lane.
// ---------------------------------------------------------------------------
__global__ __launch_bounds__(256) void softmax_kernel(float* __restrict__ part,
                                                      const float* __restrict__ mx, int sk) {
    const int wid = blockIdx.x * 4 + (threadIdx.x >> 6);  // row index in [0, B*C)
    const int lane = threadIdx.x & 63;
    const size_t PS = (size_t)B_DIM * C_DIM * C_DIM;

    f32x4 ea = (f32x4){0.f, 0.f, 0.f, 0.f}, eb = ea;
    for (int s = 0; s < sk; ++s) {
        const f32x4* row = (const f32x4*)(part + (size_t)s * PS + (size_t)wid * C_DIM + lane * 8);
        ea += row[0];
        eb += row[1];
    }
    f32x4 ma = *(const f32x4*)&mx[lane * 8];
    f32x4 mb = *(const f32x4*)&mx[lane * 8 + 4];

    float v[8];
#pragma unroll
    for (int j = 0; j < 4; ++j) v[j] = ma[j] - ea[j];
#pragma unroll
    for (int j = 0; j < 4; ++j) v[4 + j] = mb[j] - eb[j];

    float rm = v[0];
#pragma unroll
    for (int j = 1; j < 8; ++j) rm = fmaxf(rm, v[j]);
#pragma unroll
    for (int st = 1; st < 64; st <<= 1) rm = fmaxf(rm, __shfl_xor(rm, st));

    float p[8];
    float sum = 0.f;
#pragma unroll
    for (int j = 0; j < 8; ++j) {
        p[j] = expf(v[j] - rm);
        sum += p[j];
    }
#pragma unroll
    for (int st = 1; st < 64; st <<= 1) sum += __shfl_xor(sum, st);

    const float inv = 1.f / sum;
    f32x4 o0 = {p[0] * inv, p[1] * inv, p[2] * inv, p[3] * inv};
    f32x4 o1 = {p[4] * inv, p[5] * inv, p[6] * inv, p[7] * inv};
    f32x4* row0 = (f32x4*)(part + (size_t)wid * C_DIM + lane * 8);
    row0[0] = o0;
    row0[1] = o1;
}

// ---------------------------------------------------------------------------
// Kernel 4: out[b,c,n] = gamma * sum_d att[b,c,d] * Q[n,d] + x[b,c,n]
// ---------------------------------------------------------------------------
__global__ __launch_bounds__(256) void gemm2_kernel(const float* __restrict__ att,
                                                    const float* __restrict__ x,
                                                    const float* __restrict__ gamma,
                                                    float* __restrict__ out) {
    const int b = blockIdx.z;
    const int c0 = blockIdx.x * BT;  // M tile
    const int n0 = blockIdx.y * BT;  // N tile
    const float* __restrict__ A = att + (size_t)b * (C_DIM * C_DIM);
    const float* __restrict__ Q = x + (size_t)b * (N_DIM * C_DIM);
    const float* __restrict__ Xb = Q;
    float* __restrict__ Ob = out + (size_t)b * (C_DIM * N_DIM);

    __shared__ unsigned short lA[BT][BKP];
    __shared__ unsigned short lB[BT][BKP];

    const int tid = threadIdx.x;
    const int lane = tid & 63;
    const int w = tid >> 6;
    const int moff = (w & 1) * 64;
    const int noff = (w >> 1) * 64;
    const int frow = lane & 15;
    const int fk = (lane >> 4) * 8;

    f32x4 acc[4][4];
#pragma unroll
    for (int m = 0; m < 4; ++m)
#pragma unroll
        for (int n = 0; n < 4; ++n) acc[m][n] = (f32x4){0.f, 0.f, 0.f, 0.f};

    for (int k0 = 0; k0 < C_DIM; k0 += BK) {
        float4 ra[4], rb[4];
#pragma unroll
        for (int i = 0; i < 4; ++i) {
            const int f = tid + 256 * i;
            const int rr = f >> 3;
            const int k4 = (f & 7) * 4;
            ra[i] = *(const float4*)&A[(size_t)(c0 + rr) * C_DIM + k0 + k4];
            rb[i] = *(const float4*)&Q[(size_t)(n0 + rr) * C_DIM + k0 + k4];
        }
        __syncthreads();
#pragma unroll
        for (int i = 0; i < 4; ++i) {
            const int f = tid + 256 * i;
            const int rr = f >> 3;
            const int k4 = (f & 7) * 4;
            u16x4 pa = {f2bf_tr(ra[i].x), f2bf_tr(ra[i].y), f2bf_tr(ra[i].z), f2bf_tr(ra[i].w)};
            u16x4 pb = {f2bf_tr(rb[i].x), f2bf_tr(rb[i].y), f2bf_tr(rb[i].z), f2bf_tr(rb[i].w)};
            *(u16x4*)&lA[rr][k4] = pa;
            *(u16x4*)&lB[rr][k4] = pb;
        }
        __syncthreads();

        bf16x8 fa[4], fb[4];
#pragma unroll
        for (int m = 0; m < 4; ++m)
            fa[m] = as_bf(*(const u16x8*)&lA[moff + m * 16 + frow][fk]);
#pragma unroll
        for (int n = 0; n < 4; ++n)
            fb[n] = as_bf(*(const u16x8*)&lB[noff + n * 16 + frow][fk]);
#pragma unroll
        for (int m = 0; m < 4; ++m)
#pragma unroll
            for (int n = 0; n < 4; ++n)
                acc[m][n] = __builtin_amdgcn_mfma_f32_16x16x32_bf16(fa[m], fb[n], acc[m][n], 0, 0, 0);
    }

    const float g = gamma[0];
#pragma unroll
    for (int m = 0; m < 4; ++m)
#pragma unroll
        for (int n = 0; n < 4; ++n) {
            const int r = c0 + moff + m * 16 + (lane >> 4) * 4;
            const int col = n0 + noff + n * 16 + frow;
#pragma unroll
            for (int i = 0; i < 4; ++i) {
                const size_t idx = (size_t)(r + i) * N_DIM + col;
                Ob[idx] = g * acc[m][n][i] + Xb[idx];
            }
        }
}

// ---------------------------------------------------------------------------
extern "C" void kernel_launch(void* const* d_in, const int* in_sizes, int n_in,
                              void* d_out, int out_size, void* d_ws, size_t ws_size,
                              hipStream_t stream) {
    const float* x = (const float*)d_in[0];
    const float* gamma = (const float*)d_in[1];
    float* out = (float*)d_out;

    // ws layout: [mx 2KB][pmax 16KB][pad to 32KB][partials SK * 16.78MB]
    const size_t HDR = 32 * 1024;
    const size_t PSZ = (size_t)B_DIM * C_DIM * C_DIM * sizeof(float);
    int kshift = 0;
    if (ws_size >= HDR + 4 * PSZ) kshift = 2;
    else if (ws_size >= HDR + 2 * PSZ) kshift = 1;
    const int SK = 1 << kshift;

    float* mx = (float*)d_ws;
    float* pmax = mx + C_DIM;
    float* part = (float*)((char*)d_ws + HDR);

    dim3 g1(10, 1, B_DIM * SK);
    gram_kernel<<<g1, 256, 0, stream>>>(x, part, kshift);

    colmax1<<<dim3(2, 8), 256, 0, stream>>>(part, pmax, SK);
    colmax2<<<2, 256, 0, stream>>>(pmax, mx);

    softmax_kernel<<<(B_DIM * C_DIM) / 4, 256, 0, stream>>>(part, mx, SK);

    dim3 g2(C_DIM / BT, N_DIM / BT, B_DIM);  // (4,32,16)
    gemm2_kernel<<<g2, 256, 0, stream>>>(part, x, gamma, out);
}